// Round 15
// baseline (138.347 us; speedup 1.0000x reference)
//
#include <hip/hip_runtime.h>
#include <hip/hip_bf16.h>
#include <stdint.h>

#define K_TAPS 15
#define CIN    128
#define F_OUT  256
#define LSEQ   4096
#define LOUT   (LSEQ - K_TAPS + 1)   // 4082
#define BATCH  32

typedef __attribute__((ext_vector_type(8))) short bf16x8;
typedef __attribute__((ext_vector_type(4))) float f32x4;

typedef __attribute__((address_space(1))) const unsigned int gu32_t;
typedef __attribute__((address_space(3))) unsigned int su32_t;

// ---------------------------------------------------------------------------
// prep: weights fp32 [k][c][f] -> bf16 Wp, quarter-tap, PAIR-ROW granules
// (R14-verified layout; 2-way bank spread on the conv read pattern)
// ---------------------------------------------------------------------------
__global__ void prep_w_kernel(const float* __restrict__ W,
                              unsigned short* __restrict__ Wp) {
  int idx = blockIdx.x * 256 + threadIdx.x;   // 15*128*256 = 491520 total
  int f  = idx & 255;
  int kc = idx >> 8;
  int c  = kc & 127;
  int k  = kc >> 7;
  float w = W[idx];
  __hip_bfloat16 hb = __float2bfloat16(w);
  int q  = c >> 5;
  int kl = (c >> 3) & 3;
  int c7 = c & 7;
  int nt = f >> 7;
  int fl = f & 127;
  int pr = fl >> 1;
  int s8 = ((fl & 1) * 4 + kl) ^ (pr & 7);
  size_t G = (size_t)((k * 4 + q) * 2 + nt) * 512 + pr * 8 + s8;
  Wp[G * 8 + c7] = *reinterpret_cast<unsigned short*>(&hb);
}

// ---------------------------------------------------------------------------
// sq[b*4096+l] = sum_c x[b][l][c]^2  (R11-verified; fusion refuted 3x)
// ---------------------------------------------------------------------------
__global__ void sq_kernel(const float* __restrict__ x, float* __restrict__ sq) {
  int wid  = threadIdx.x >> 6;
  int lane = threadIdx.x & 63;
  int half = lane >> 5;
  int lq   = lane & 31;
  long pos = (long)blockIdx.x * 8 + wid * 2 + half;   // < 32*4096
  const float4* xp = (const float4*)(x + pos * CIN) + lq;
  float4 v = *xp;
  float s = v.x * v.x + v.y * v.y + v.z * v.z + v.w * v.w;
  #pragma unroll
  for (int m = 1; m <= 16; m <<= 1) s += __shfl_xor(s, m, 64);
  if (lq == 0) sq[pos] = s;
}

// ---------------------------------------------------------------------------
// rn[b*4096+t] = scale / sqrt( sum_{k<15} sq[b][t+k] + 1e-7 )
// ---------------------------------------------------------------------------
__global__ void rn_kernel(const float* __restrict__ sq,
                          const float* __restrict__ scale,
                          float* __restrict__ rn) {
  int t = blockIdx.x * 256 + threadIdx.x;
  int b = blockIdx.y;
  if (t >= LOUT) return;
  const float* s = sq + b * LSEQ + t;
  float w = 0.f;
  #pragma unroll
  for (int k = 0; k < K_TAPS; ++k) w += s[k];
  rn[b * LSEQ + t] = scale[0] / sqrtf(w + 1e-7f);
}

// ---------------------------------------------------------------------------
// main implicit-GEMM conv -- R14 structure (3 blocks/CU, pair-row B swizzle,
// 118.3 us verified) with SINGLE-barrier double-buffer:
//   per phase: A ds_reads -> vmcnt(0) [own stage(ph) landed] -> barrier
//   [all waves' stage(ph) visible AND all waves done reading buf^1] ->
//   stage(ph+1) into buf^1 [race-free by the barrier] -> B ds_reads ->
//   lgkm(0) -> MFMA.  The acquire barrier doubles as the release: a wave's
//   buf-reads drain at its lgkm(0) before it can reach the next barrier.
//   60 barriers instead of 120; issue-to-wait distance stays ~1 phase body.
// ---------------------------------------------------------------------------
#define BM 128
#define BN 128
#define XROWS 144
#define XBYTES (XROWS * 256)   // 36864
#define BBYTES 8192            // one [64 pair-rows][8 slots][16B] buffer
#define NPHASE (K_TAPS * 4)    // 60

__global__ __launch_bounds__(256, 3) void conv_gemm_kernel(
    const float* __restrict__ x, const unsigned short* __restrict__ Wp,
    const float* __restrict__ rn, const float* __restrict__ bias,
    float* __restrict__ out)
{
  __shared__ __align__(16) char lds[XBYTES + 2 * BBYTES];  // 53248 B
  char* Xs = lds;
  char* Bs = lds + XBYTES;

  const int b     = blockIdx.y;
  const int mtile = blockIdx.x >> 1;
  const int ntile = blockIdx.x & 1;
  const int t0    = mtile * BM;
  const int n0    = ntile * BN;

  const int tx   = threadIdx.x;
  const int wid  = tx >> 6;
  const int lane = tx & 63;
  const int wm   = wid >> 1;
  const int wn   = wid & 1;

  // ---- B staging: one 8 KB quarter-tap slice, contiguous src, linear dest
  auto stageB = [&](int buf, int phase) {
    const char* src = (const char*)Wp + ((size_t)phase * 2 + ntile) * 8192;
    char* dst = Bs + buf * BBYTES;
    int base = wid * 2048;
    #pragma unroll
    for (int i = 0; i < 2; ++i) {
      int off = base + i * 1024;
      __builtin_amdgcn_global_load_lds(
          (gu32_t*)(src + off + lane * 16),
          (su32_t*)(dst + off), 16, 0, 0);
    }
  };

  stageB(0, 0);   // overlaps with X staging below; drained by __syncthreads

  // ---- stage X once: 144 rows x 128 ch, fp32 -> bf16, XOR-swizzled
  //      (byte-identical to the R3/R11/R13/R14 verified staging loop)
  {
    const int rloc = tx >> 4;    // row within 16-row slab
    const int g    = tx & 15;    // 16B granule (8 chans)
    const float* xb = x + (long)b * LSEQ * CIN;
    #pragma unroll
    for (int it = 0; it < 9; ++it) {
      int row  = it * 16 + rloc;
      int grow = t0 + row;
      float v[8];
      if (grow < LSEQ) {
        const float4* p = (const float4*)(xb + (long)grow * CIN + g * 8);
        float4 a0 = p[0], a1 = p[1];
        v[0]=a0.x; v[1]=a0.y; v[2]=a0.z; v[3]=a0.w;
        v[4]=a1.x; v[5]=a1.y; v[6]=a1.z; v[7]=a1.w;
      } else {
        #pragma unroll
        for (int j = 0; j < 8; ++j) v[j] = 0.f;
      }
      union { unsigned short us[8]; int4 q; } pk;
      #pragma unroll
      for (int j = 0; j < 8; ++j) {
        __hip_bfloat16 hb = __float2bfloat16(v[j]);
        pk.us[j] = *reinterpret_cast<unsigned short*>(&hb);
      }
      int slot = (g & 8) | ((g ^ row) & 7);
      *(int4*)(Xs + row * 256 + slot * 16) = pk.q;
    }
  }
  __syncthreads();   // X ready + stage(0) drained; vmcnt=0 at loop entry

  f32x4 acc[4][4] = {};   // [m][n], accumulate across ALL phases

  const int klane = lane >> 4;   // 0..3
  const int rl    = lane & 15;
  const int arow0 = wm * 64;
  const int bcol0 = wn * 64;

  #pragma unroll 4
  for (int ph = 0; ph < NPHASE; ++ph) {
    const int buf = ph & 1;
    const int tap = ph >> 2;
    const int qtr = ph & 3;

    // A ds_reads -- Xs is immutable, safe anywhere
    const int ga = qtr * 4 + klane;          // A granule 0..15
    bf16x8 af[4];
    #pragma unroll
    for (int mf = 0; mf < 4; ++mf) {
      int row  = arow0 + mf * 16 + rl + tap;
      int slot = (ga & 8) | ((ga ^ row) & 7);
      af[mf] = *(const bf16x8*)(Xs + row * 256 + slot * 16);
    }

    // own stage(ph) loads landed (issued just after the previous barrier,
    // ~1 phase body ago)
    asm volatile("s_waitcnt vmcnt(0)" ::: "memory");
    // single barrier: all waves' stage(ph) visible AND all waves finished
    // their buf^1 reads in phase ph-1 (lgkm(0) preceded their MFMA)
    __builtin_amdgcn_s_barrier();

    // issue next-phase prefetch into the just-released buffer
    if (ph + 1 < NPHASE) stageB(buf ^ 1, ph + 1);

    const char* Bsc = Bs + buf * BBYTES;
    bf16x8 bfr[4];
    #pragma unroll
    for (int nf = 0; nf < 4; ++nf) {
      int fl = bcol0 + nf * 16 + rl;
      int pr = fl >> 1;
      int s8 = ((fl & 1) * 4 + klane) ^ (pr & 7);
      bfr[nf] = *(const bf16x8*)(Bsc + (pr * 8 + s8) * 16);
    }

    asm volatile("s_waitcnt lgkmcnt(0)" ::: "memory");
    __builtin_amdgcn_s_setprio(1);
    #pragma unroll
    for (int mf = 0; mf < 4; ++mf)
      #pragma unroll
      for (int nf = 0; nf < 4; ++nf)
        acc[mf][nf] = __builtin_amdgcn_mfma_f32_16x16x32_bf16(
            af[mf], bfr[nf], acc[mf][nf], 0, 0, 0);
    __builtin_amdgcn_s_setprio(0);
  }

  // ---- epilogue: out = acc * rn[row] + bias[f]
  // C/D layout: col = lane&15, row = (lane>>4)*4 + reg  [m89-verified]
  const int rgrp = lane >> 4;
  float biasv[4];
  #pragma unroll
  for (int nf = 0; nf < 4; ++nf) biasv[nf] = bias[n0 + bcol0 + nf * 16 + rl];
  float* ob = out + (long)b * LOUT * F_OUT;
  const float* rnb = rn + b * LSEQ + t0;
  #pragma unroll
  for (int mf = 0; mf < 4; ++mf) {
    #pragma unroll
    for (int r = 0; r < 4; ++r) {
      int row = arow0 + mf * 16 + rgrp * 4 + r;
      int gt  = t0 + row;
      if (gt < LOUT) {
        float rv = rnb[row];
        #pragma unroll
        for (int nf = 0; nf < 4; ++nf) {
          ob[(long)gt * F_OUT + n0 + bcol0 + nf * 16 + rl] =
              acc[mf][nf][r] * rv + biasv[nf];
        }
      }
    }
  }
}

// ---------------------------------------------------------------------------
extern "C" void kernel_launch(void* const* d_in, const int* in_sizes, int n_in,
                              void* d_out, int out_size, void* d_ws, size_t ws_size,
                              hipStream_t stream) {
  const float* x     = (const float*)d_in[0];   // (32, 4096, 128)
  const float* W     = (const float*)d_in[1];   // (15, 128, 256)
  const float* scale = (const float*)d_in[2];   // (1,1,1)
  const float* bias  = (const float*)d_in[3];   // (256,)
  float* out = (float*)d_out;                   // (32, 4082, 256)

  char* ws = (char*)d_ws;
  unsigned short* Wp = (unsigned short*)ws;                  // 983040 B
  float* sq = (float*)(ws + 1048576);                        // 524288 B
  float* rn = (float*)(ws + 1048576 + 524288);               // 524288 B

  prep_w_kernel<<<1920, 256, 0, stream>>>(W, Wp);
  sq_kernel<<<BATCH * LSEQ / 8, 256, 0, stream>>>(x, sq);
  rn_kernel<<<dim3((LOUT + 255) / 256, BATCH), 256, 0, stream>>>(sq, scale, rn);
  conv_gemm_kernel<<<dim3(64, BATCH), 256, 0, stream>>>(x, Wp, rn, bias, out);
}

// Round 16
// 136.686 us; speedup vs baseline: 1.0122x; 1.0122x over previous
//
#include <hip/hip_runtime.h>
#include <hip/hip_bf16.h>
#include <stdint.h>

#define K_TAPS 15
#define CIN    128
#define F_OUT  256
#define LSEQ   4096
#define LOUT   (LSEQ - K_TAPS + 1)   // 4082
#define BATCH  32

typedef __attribute__((ext_vector_type(8))) short bf16x8;
typedef __attribute__((ext_vector_type(4))) float f32x4;

typedef __attribute__((address_space(1))) const unsigned int gu32_t;
typedef __attribute__((address_space(3))) unsigned int su32_t;

// ---------------------------------------------------------------------------
// merged prep + sq (independent ops, disjoint block ranges, one launch):
//   blocks [0, 1920):      weights fp32 [k][c][f] -> bf16 Wp, quarter-tap
//                          pair-row layout (R14-verified swizzle bake)
//   blocks [1920, 18304):  sq[b*4096+l] = sum_c x[b][l][c]^2
// ---------------------------------------------------------------------------
#define PREP_BLOCKS 1920
__global__ void prep_sq_kernel(const float* __restrict__ W,
                               unsigned short* __restrict__ Wp,
                               const float* __restrict__ x,
                               float* __restrict__ sq) {
  if (blockIdx.x < PREP_BLOCKS) {
    int idx = blockIdx.x * 256 + threadIdx.x;   // 15*128*256 = 491520 total
    int f  = idx & 255;
    int kc = idx >> 8;
    int c  = kc & 127;
    int k  = kc >> 7;
    float w = W[idx];
    __hip_bfloat16 hb = __float2bfloat16(w);
    int q  = c >> 5;
    int kl = (c >> 3) & 3;
    int c7 = c & 7;
    int nt = f >> 7;
    int fl = f & 127;
    int pr = fl >> 1;
    int s8 = ((fl & 1) * 4 + kl) ^ (pr & 7);
    size_t G = (size_t)((k * 4 + q) * 2 + nt) * 512 + pr * 8 + s8;
    Wp[G * 8 + c7] = *reinterpret_cast<unsigned short*>(&hb);
  } else {
    int bid  = blockIdx.x - PREP_BLOCKS;
    int wid  = threadIdx.x >> 6;
    int lane = threadIdx.x & 63;
    int half = lane >> 5;
    int lq   = lane & 31;
    long pos = (long)bid * 8 + wid * 2 + half;   // < 32*4096
    const float4* xp = (const float4*)(x + pos * CIN) + lq;
    float4 v = *xp;
    float s = v.x * v.x + v.y * v.y + v.z * v.z + v.w * v.w;
    #pragma unroll
    for (int m = 1; m <= 16; m <<= 1) s += __shfl_xor(s, m, 64);
    if (lq == 0) sq[pos] = s;
  }
}

// ---------------------------------------------------------------------------
// rn[b*4096+t] = scale / sqrt( sum_{k<15} sq[b][t+k] + 1e-7 )
// ---------------------------------------------------------------------------
__global__ void rn_kernel(const float* __restrict__ sq,
                          const float* __restrict__ scale,
                          float* __restrict__ rn) {
  int t = blockIdx.x * 256 + threadIdx.x;
  int b = blockIdx.y;
  if (t >= LOUT) return;
  const float* s = sq + b * LSEQ + t;
  float w = 0.f;
  #pragma unroll
  for (int k = 0; k < K_TAPS; ++k) w += s[k];
  rn[b * LSEQ + t] = scale[0] / sqrtf(w + 1e-7f);
}

// ---------------------------------------------------------------------------
// main implicit-GEMM conv -- R14 verified source, BYTE-IDENTICAL (118.3 us,
// MfmaUtil 52.1, 3 blocks/CU, pair-row B swizzle, counted vmcnt(2) dbuf).
// block: 256 thr (4 waves, 2x2 wave grid, 64x64 per wave) -> 128M x 128N
// LDS: Xs [144 rows][128 ch] bf16 swizzled + Bs dbuf 2x8KB = 53248 B -> 3/CU
// K loop: 60 phases (tap x quarter); counted vmcnt(2) dbuf + setprio
// ---------------------------------------------------------------------------
#define BM 128
#define BN 128
#define XROWS 144
#define XBYTES (XROWS * 256)   // 36864
#define BBYTES 8192            // one [64 pair-rows][8 slots][16B] buffer
#define NPHASE (K_TAPS * 4)    // 60

__global__ __launch_bounds__(256, 3) void conv_gemm_kernel(
    const float* __restrict__ x, const unsigned short* __restrict__ Wp,
    const float* __restrict__ rn, const float* __restrict__ bias,
    float* __restrict__ out)
{
  __shared__ __align__(16) char lds[XBYTES + 2 * BBYTES];  // 53248 B
  char* Xs = lds;
  char* Bs = lds + XBYTES;

  const int b     = blockIdx.y;
  const int mtile = blockIdx.x >> 1;
  const int ntile = blockIdx.x & 1;
  const int t0    = mtile * BM;
  const int n0    = ntile * BN;

  const int tx   = threadIdx.x;
  const int wid  = tx >> 6;
  const int lane = tx & 63;
  const int wm   = wid >> 1;
  const int wn   = wid & 1;

  // ---- B staging: one 8 KB quarter-tap slice, contiguous src, linear dest
  auto stageB = [&](int buf, int phase) {
    const char* src = (const char*)Wp + ((size_t)phase * 2 + ntile) * 8192;
    char* dst = Bs + buf * BBYTES;
    int base = wid * 2048;
    #pragma unroll
    for (int i = 0; i < 2; ++i) {
      int off = base + i * 1024;
      __builtin_amdgcn_global_load_lds(
          (gu32_t*)(src + off + lane * 16),
          (su32_t*)(dst + off), 16, 0, 0);
    }
  };

  stageB(0, 0);   // overlaps with X staging below; drained by __syncthreads

  // ---- stage X once: 144 rows x 128 ch, fp32 -> bf16, XOR-swizzled
  {
    const int rloc = tx >> 4;    // row within 16-row slab
    const int g    = tx & 15;    // 16B granule (8 chans)
    const float* xb = x + (long)b * LSEQ * CIN;
    #pragma unroll
    for (int it = 0; it < 9; ++it) {
      int row  = it * 16 + rloc;
      int grow = t0 + row;
      float v[8];
      if (grow < LSEQ) {
        const float4* p = (const float4*)(xb + (long)grow * CIN + g * 8);
        float4 a0 = p[0], a1 = p[1];
        v[0]=a0.x; v[1]=a0.y; v[2]=a0.z; v[3]=a0.w;
        v[4]=a1.x; v[5]=a1.y; v[6]=a1.z; v[7]=a1.w;
      } else {
        #pragma unroll
        for (int j = 0; j < 8; ++j) v[j] = 0.f;
      }
      union { unsigned short us[8]; int4 q; } pk;
      #pragma unroll
      for (int j = 0; j < 8; ++j) {
        __hip_bfloat16 hb = __float2bfloat16(v[j]);
        pk.us[j] = *reinterpret_cast<unsigned short*>(&hb);
      }
      int slot = (g & 8) | ((g ^ row) & 7);
      *(int4*)(Xs + row * 256 + slot * 16) = pk.q;
    }
  }
  __syncthreads();   // X ready + stage(0) drained; vmcnt=0 at loop entry

  f32x4 acc[4][4] = {};   // [m][n], accumulate across ALL phases

  const int klane = lane >> 4;   // 0..3
  const int rl    = lane & 15;
  const int arow0 = wm * 64;
  const int bcol0 = wn * 64;

  #pragma unroll 4
  for (int ph = 0; ph < NPHASE; ++ph) {
    const int buf = ph & 1;
    const int tap = ph >> 2;
    const int qtr = ph & 3;

    // issue next-phase B prefetch (stays in flight across the barrier)
    if (ph + 1 < NPHASE) stageB(buf ^ 1, ph + 1);

    // hoist A ds_reads -- Xs is immutable, no barrier needed
    const int ga = qtr * 4 + klane;          // A granule 0..15
    bf16x8 af[4];
    #pragma unroll
    for (int mf = 0; mf < 4; ++mf) {
      int row  = arow0 + mf * 16 + rl + tap;
      int slot = (ga & 8) | ((ga ^ row) & 7);
      af[mf] = *(const bf16x8*)(Xs + row * 256 + slot * 16);
    }

    // counted wait: drain only THIS phase's B loads, keep next 2 in flight
    if (ph + 1 < NPHASE) {
      asm volatile("s_waitcnt vmcnt(2)" ::: "memory");
    } else {
      asm volatile("s_waitcnt vmcnt(0)" ::: "memory");
    }
    __builtin_amdgcn_s_barrier();      // buf(ph) ready in all waves

    const char* Bsc = Bs + buf * BBYTES;
    bf16x8 bfr[4];
    #pragma unroll
    for (int nf = 0; nf < 4; ++nf) {
      int fl = bcol0 + nf * 16 + rl;
      int pr = fl >> 1;
      int s8 = ((fl & 1) * 4 + klane) ^ (pr & 7);
      bfr[nf] = *(const bf16x8*)(Bsc + (pr * 8 + s8) * 16);
    }

    __builtin_amdgcn_s_setprio(1);
    #pragma unroll
    for (int mf = 0; mf < 4; ++mf)
      #pragma unroll
      for (int nf = 0; nf < 4; ++nf)
        acc[mf][nf] = __builtin_amdgcn_mfma_f32_16x16x32_bf16(
            af[mf], bfr[nf], acc[mf][nf], 0, 0, 0);
    __builtin_amdgcn_s_setprio(0);

    // buf's ds_reads complete before next phase's stage may overwrite it
    asm volatile("s_waitcnt lgkmcnt(0)" ::: "memory");
    __builtin_amdgcn_s_barrier();
  }

  // ---- epilogue: out = acc * rn[row] + bias[f]
  // C/D layout: col = lane&15, row = (lane>>4)*4 + reg  [m89-verified]
  const int rgrp = lane >> 4;
  float biasv[4];
  #pragma unroll
  for (int nf = 0; nf < 4; ++nf) biasv[nf] = bias[n0 + bcol0 + nf * 16 + rl];
  float* ob = out + (long)b * LOUT * F_OUT;
  const float* rnb = rn + b * LSEQ + t0;
  #pragma unroll
  for (int mf = 0; mf < 4; ++mf) {
    #pragma unroll
    for (int r = 0; r < 4; ++r) {
      int row = arow0 + mf * 16 + rgrp * 4 + r;
      int gt  = t0 + row;
      if (gt < LOUT) {
        float rv = rnb[row];
        #pragma unroll
        for (int nf = 0; nf < 4; ++nf) {
          ob[(long)gt * F_OUT + n0 + bcol0 + nf * 16 + rl] =
              acc[mf][nf][r] * rv + biasv[nf];
        }
      }
    }
  }
}

// ---------------------------------------------------------------------------
extern "C" void kernel_launch(void* const* d_in, const int* in_sizes, int n_in,
                              void* d_out, int out_size, void* d_ws, size_t ws_size,
                              hipStream_t stream) {
  const float* x     = (const float*)d_in[0];   // (32, 4096, 128)
  const float* W     = (const float*)d_in[1];   // (15, 128, 256)
  const float* scale = (const float*)d_in[2];   // (1,1,1)
  const float* bias  = (const float*)d_in[3];   // (256,)
  float* out = (float*)d_out;                   // (32, 4082, 256)

  char* ws = (char*)d_ws;
  unsigned short* Wp = (unsigned short*)ws;                  // 983040 B
  float* sq = (float*)(ws + 1048576);                        // 524288 B
  float* rn = (float*)(ws + 1048576 + 524288);               // 524288 B

  prep_sq_kernel<<<PREP_BLOCKS + BATCH * LSEQ / 8, 256, 0, stream>>>(W, Wp, x, sq);
  rn_kernel<<<dim3((LOUT + 255) / 256, BATCH), 256, 0, stream>>>(sq, scale, rn);
  conv_gemm_kernel<<<dim3(64, BATCH), 256, 0, stream>>>(x, Wp, rn, bias, out);
}